// Round 2
// baseline (4154.267 us; speedup 1.0000x reference)
//
#include <hip/hip_runtime.h>

#define NODES 100000
#define EDGES 1600000
#define FEATS 128
#define NCLS  16

// bucket partition: 64 dst-nodes per bucket
#define BSH    6
#define BNODES 64
#define NB     ((NODES + BNODES - 1) / BNODES)   // 1563
#define BCAP   2048                               // mean 1024, sd 32 -> 2048 is >30 sigma

typedef unsigned int  u32;
typedef unsigned short u16;
typedef __attribute__((ext_vector_type(8))) short short8;
typedef __attribute__((ext_vector_type(4))) float f32x4;

__device__ __forceinline__ float b2f(u16 v){ return __uint_as_float(((u32)v)<<16); }
__device__ __forceinline__ u16 f2b(float f){
  u32 u = __float_as_uint(f);
  u += 0x7fffu + ((u>>16)&1u);   // RNE
  return (u16)(u>>16);
}
__device__ __forceinline__ float blo(u32 p){ return __uint_as_float(p<<16); }
__device__ __forceinline__ float bhi(u32 p){ return __uint_as_float(p & 0xffff0000u); }

// ---------------- edge partition into dst-buckets ----------------
// packed edge word: (dst & 63) << 17 | src   (src < 2^17)

__global__ void part_k(const int* __restrict__ src, const int* __restrict__ dst,
                       int* __restrict__ bcnt, u32* __restrict__ elist, int E){
  int i = blockIdx.x*256 + threadIdx.x;
  if (i < E){
    int d = dst[i];
    int b = d >> BSH;
    int p = atomicAdd(&bcnt[b], 1);
    if (p < BCAP)
      elist[(size_t)b*BCAP + p] = ((u32)(d & (BNODES-1)) << 17) | (u32)src[i];
  }
}

// ---------------- per-bucket degree -> inv_deg ----------------

__global__ __launch_bounds__(256) void bdeg_k(const u32* __restrict__ elist,
    const int* __restrict__ bcnt, float* __restrict__ invd, int M){
  __shared__ int h[BNODES];
  int b = blockIdx.x, t = threadIdx.x;
  if (t < BNODES) h[t] = 0;
  __syncthreads();
  int cnt = bcnt[b];
  const u32* el = elist + (size_t)b*BCAP;
  for (int e = t; e < cnt; e += 256) atomicAdd(&h[el[e]>>17], 1);
  __syncthreads();
  if (t < BNODES){
    int v = b*BNODES + t;
    if (v < M) invd[v] = 1.f / fmaxf((float)h[t], 1.f);
  }
}

// ---------------- dtype conversion ----------------

__global__ void convf_k(const float* __restrict__ in, u16* __restrict__ o, int n4){
  int i = blockIdx.x*256 + threadIdx.x;
  if (i < n4){
    float4 x = ((const float4*)in)[i];
    ushort4 r;
    r.x = f2b(x.x); r.y = f2b(x.y); r.z = f2b(x.z); r.w = f2b(x.w);
    ((ushort4*)o)[i] = r;
  }
}

// W[K][N] row-major -> Wt[N][K] bf16
__global__ void convw_k(const float* __restrict__ W, u16* __restrict__ Wt, int Kd, int Nd){
  int i = blockIdx.x*256 + threadIdx.x;
  if (i < Kd*Nd){
    int k = i / Nd, nn = i - k*Nd;
    Wt[nn*Kd + k] = f2b(W[i]);
  }
}

// ---------------- GEMM: y[M x N] = h[M x 128] * W  (Wt is [N][128] bf16) ----------------

template<int NT>
__global__ __launch_bounds__(256) void gemm_k(const u16* __restrict__ h,
                                              const u16* __restrict__ Wt,
                                              u16* __restrict__ y, int M){
  const int K = FEATS;
  const int N = NT*16;
  int lane = threadIdx.x & 63;
  int wave = threadIdx.x >> 6;
  int m    = lane & 15;
  int quad = lane >> 4;
  int row0 = (blockIdx.x*4 + wave)*16;
  if (row0 >= M) return;
  int rowA = row0 + m; if (rowA > M-1) rowA = M-1;
  const u16* pa = h + (size_t)rowA*K + quad*8;

  f32x4 acc[NT];
  #pragma unroll
  for (int j=0;j<NT;++j) acc[j] = (f32x4){0.f,0.f,0.f,0.f};

  #pragma unroll
  for (int kk=0; kk<K; kk+=32){
    short8 a = *(const short8*)(pa + kk);
    #pragma unroll
    for (int j=0;j<NT;++j){
      short8 b = *(const short8*)(Wt + (size_t)(j*16 + m)*K + kk + quad*8);
      acc[j] = __builtin_amdgcn_mfma_f32_16x16x32_bf16(a, b, acc[j], 0, 0, 0);
    }
  }

  #pragma unroll
  for (int j=0;j<NT;++j){
    #pragma unroll
    for (int r=0;r<4;++r){
      int row = row0 + quad*4 + r;                  // C/D: row = quad*4 + reg
      if (row < M) y[(size_t)row*N + j*16 + m] = f2b(acc[j][r]);  // col = lane&15
    }
  }
}

// ---------------- 128-feat aggregation epilogue (layers 0..2) ----------------
// one block per bucket; LDS f32 accum [64 nodes][128 feats] = 32KB.
// out = relu((1+eps)*y[v] + inv_deg * sum_{src->v} y[src] + b)

__global__ __launch_bounds__(256) void aggL_k(const u32* __restrict__ y2,
    const u32* __restrict__ elist, const int* __restrict__ bcnt,
    const float* __restrict__ invd, const float* __restrict__ bias,
    const float* __restrict__ epsv, int ei, u32* __restrict__ hout, int M){
  __shared__ float acc[BNODES*FEATS];
  int b = blockIdx.x;
  int lane = threadIdx.x & 63;
  int wv = __builtin_amdgcn_readfirstlane(threadIdx.x >> 6);
  for (int i = threadIdx.x; i < BNODES*FEATS; i += 256) acc[i] = 0.f;
  __syncthreads();

  int cnt = bcnt[b];
  const u32* el = elist + (size_t)b*BCAP;
  int chunk = (cnt + 3) >> 2;
  int e0 = wv*chunk;   if (e0 > cnt) e0 = cnt;
  int e1 = e0 + chunk; if (e1 > cnt) e1 = cnt;
  int e = e0;
  for (; e + 4 <= e1; e += 4){
    u32 w0 = el[e+0], w1 = el[e+1], w2 = el[e+2], w3 = el[e+3];
    u32 p0 = y2[(size_t)(w0 & 0x1FFFFu)*64 + lane];
    u32 p1 = y2[(size_t)(w1 & 0x1FFFFu)*64 + lane];
    u32 p2 = y2[(size_t)(w2 & 0x1FFFFu)*64 + lane];
    u32 p3 = y2[(size_t)(w3 & 0x1FFFFu)*64 + lane];
    float* a0 = &acc[(w0>>17)*FEATS + lane*2];
    float* a1 = &acc[(w1>>17)*FEATS + lane*2];
    float* a2 = &acc[(w2>>17)*FEATS + lane*2];
    float* a3 = &acc[(w3>>17)*FEATS + lane*2];
    atomicAdd(a0,   blo(p0)); atomicAdd(a0+1, bhi(p0));
    atomicAdd(a1,   blo(p1)); atomicAdd(a1+1, bhi(p1));
    atomicAdd(a2,   blo(p2)); atomicAdd(a2+1, bhi(p2));
    atomicAdd(a3,   blo(p3)); atomicAdd(a3+1, bhi(p3));
  }
  for (; e < e1; ++e){
    u32 w0 = el[e];
    u32 p0 = y2[(size_t)(w0 & 0x1FFFFu)*64 + lane];
    float* a0 = &acc[(w0>>17)*FEATS + lane*2];
    atomicAdd(a0,   blo(p0)); atomicAdd(a0+1, bhi(p0));
  }
  __syncthreads();

  float e1s = 1.f + epsv[ei];
  for (int ni = wv; ni < BNODES; ni += 4){
    int v = b*BNODES + ni;
    if (v < M){
      u32 pv = y2[(size_t)v*64 + lane];
      float inv = invd[v];
      float o0 = e1s*blo(pv) + inv*acc[ni*FEATS + lane*2]   + bias[lane*2];
      float o1 = e1s*bhi(pv) + inv*acc[ni*FEATS + lane*2+1] + bias[lane*2+1];
      o0 = fmaxf(o0, 0.f); o1 = fmaxf(o1, 0.f);
      hout[(size_t)v*64 + lane] = (u32)f2b(o0) | ((u32)f2b(o1) << 16);
    }
  }
}

// ---------------- final 16-feat aggregation, f32 out, no relu ----------------

__global__ __launch_bounds__(256) void aggF_k(const u16* __restrict__ y,
    const u32* __restrict__ elist, const int* __restrict__ bcnt,
    const float* __restrict__ invd, const float* __restrict__ bias,
    const float* __restrict__ epsv, float* __restrict__ out, int M){
  __shared__ float acc[BNODES*NCLS];
  int b = blockIdx.x, t = threadIdx.x;
  int lane = t & 63;
  int wv = __builtin_amdgcn_readfirstlane(t >> 6);
  int feat = lane & 15, sub = lane >> 4;
  for (int i = t; i < BNODES*NCLS; i += 256) acc[i] = 0.f;
  __syncthreads();

  int cnt = bcnt[b];
  const u32* el = elist + (size_t)b*BCAP;
  int chunk = (cnt + 3) >> 2;
  int e0 = wv*chunk;   if (e0 > cnt) e0 = cnt;
  int e1 = e0 + chunk; if (e1 > cnt) e1 = cnt;
  int e = e0;
  for (; e + 4 <= e1; e += 4){
    u32 w0 = el[e+0], w1 = el[e+1], w2 = el[e+2], w3 = el[e+3];
    u32 ws = (sub == 0) ? w0 : (sub == 1) ? w1 : (sub == 2) ? w2 : w3;
    float val = b2f(y[(size_t)(ws & 0x1FFFFu)*NCLS + feat]);
    atomicAdd(&acc[(ws>>17)*NCLS + feat], val);
  }
  for (; e < e1; ++e){
    if (sub == 0){
      u32 w0 = el[e];
      float val = b2f(y[(size_t)(w0 & 0x1FFFFu)*NCLS + feat]);
      atomicAdd(&acc[(w0>>17)*NCLS + feat], val);
    }
  }
  __syncthreads();

  float e1s = 1.f + epsv[3];
  for (int i = t; i < BNODES*NCLS; i += 256){
    int ni = i >> 4, f = i & 15;
    int v = b*BNODES + ni;
    if (v < M)
      out[(size_t)v*NCLS + f] = e1s*b2f(y[(size_t)v*NCLS + f]) + invd[v]*acc[i] + bias[f];
  }
}

// ---------------- launch ----------------

extern "C" void kernel_launch(void* const* d_in, const int* in_sizes, int n_in,
                              void* d_out, int out_size, void* d_ws, size_t ws_size,
                              hipStream_t stream){
  const float* feats = (const float*)d_in[0];
  const int*   src   = (const int*)d_in[1];
  const int*   dst   = (const int*)d_in[2];
  const float* W0 = (const float*)d_in[3];  const float* b0 = (const float*)d_in[4];
  const float* W1 = (const float*)d_in[5];  const float* b1 = (const float*)d_in[6];
  const float* W2 = (const float*)d_in[7];  const float* b2 = (const float*)d_in[8];
  const float* W3 = (const float*)d_in[9];  const float* b3 = (const float*)d_in[10];
  const float* eps = (const float*)d_in[11];

  char* w = (char*)d_ws;
  auto alloc = [&](size_t bytes)->char*{
    char* p = w; w += (bytes + 255) & ~(size_t)255; return p;
  };
  int*  bcnt = (int*)alloc(sizeof(int)*NB);
  float* invd = (float*)alloc(sizeof(float)*NODES);
  u32*  elist = (u32*)alloc(sizeof(u32)*(size_t)NB*BCAP);
  u16*  hb   = (u16*)alloc(sizeof(u16)*(size_t)NODES*FEATS);
  u16*  yb   = (u16*)alloc(sizeof(u16)*(size_t)NODES*FEATS);
  u16*  Wt0  = (u16*)alloc(sizeof(u16)*128*128);
  u16*  Wt1  = (u16*)alloc(sizeof(u16)*128*128);
  u16*  Wt2  = (u16*)alloc(sizeof(u16)*128*128);
  u16*  Wt3  = (u16*)alloc(sizeof(u16)*16*128);

  // ---- bucket partition + degrees ----
  hipMemsetAsync(bcnt, 0, sizeof(int)*NB, stream);
  part_k<<<(EDGES+255)/256, 256, 0, stream>>>(src, dst, bcnt, elist, EDGES);
  bdeg_k<<<NB, 256, 0, stream>>>(elist, bcnt, invd, NODES);

  // ---- convert inputs to bf16 ----
  convf_k<<<((NODES*FEATS/4)+255)/256, 256, 0, stream>>>(feats, hb, NODES*FEATS/4);
  convw_k<<<(128*128+255)/256, 256, 0, stream>>>(W0, Wt0, 128, 128);
  convw_k<<<(128*128+255)/256, 256, 0, stream>>>(W1, Wt1, 128, 128);
  convw_k<<<(128*128+255)/256, 256, 0, stream>>>(W2, Wt2, 128, 128);
  convw_k<<<(128*16 +255)/256, 256, 0, stream>>>(W3, Wt3, 128, 16);

  int gblocks = (NODES + 63)/64;

  // layers 0..2: y = h@W ; h = relu((1+eps)y + mean_agg(y) + b)
  gemm_k<8><<<gblocks, 256, 0, stream>>>(hb, Wt0, yb, NODES);
  aggL_k<<<NB, 256, 0, stream>>>((const u32*)yb, elist, bcnt, invd, b0, eps, 0, (u32*)hb, NODES);
  gemm_k<8><<<gblocks, 256, 0, stream>>>(hb, Wt1, yb, NODES);
  aggL_k<<<NB, 256, 0, stream>>>((const u32*)yb, elist, bcnt, invd, b1, eps, 1, (u32*)hb, NODES);
  gemm_k<8><<<gblocks, 256, 0, stream>>>(hb, Wt2, yb, NODES);
  aggL_k<<<NB, 256, 0, stream>>>((const u32*)yb, elist, bcnt, invd, b2, eps, 2, (u32*)hb, NODES);

  // layer 3: y = h@W3 (N=16); out = (1+eps)y + mean_agg(y) + b  (f32, no relu)
  gemm_k<1><<<gblocks, 256, 0, stream>>>(hb, Wt3, yb, NODES);
  aggF_k<<<NB, 256, 0, stream>>>(yb, elist, bcnt, invd, b3, eps, (float*)d_out, NODES);
}

// Round 3
// 728.816 us; speedup vs baseline: 5.7000x; 5.7000x over previous
//
#include <hip/hip_runtime.h>

#define NODES 100000
#define EDGES 1600000
#define FEATS 128
#define NCLS  16

// bucket partition: 64 dst-nodes per bucket
#define BSH    6
#define BNODES 64
#define NB     ((NODES + BNODES - 1) / BNODES)   // 1563
#define BCAP   2048                               // mean 1024, sd ~32

typedef unsigned int  u32;
typedef unsigned short u16;
typedef __attribute__((ext_vector_type(8))) short short8;
typedef __attribute__((ext_vector_type(4))) float f32x4;

__device__ __forceinline__ float b2f(u16 v){ return __uint_as_float(((u32)v)<<16); }
__device__ __forceinline__ u16 f2b(float f){
  u32 u = __float_as_uint(f);
  u += 0x7fffu + ((u>>16)&1u);   // RNE
  return (u16)(u>>16);
}
__device__ __forceinline__ float blo(u32 p){ return __uint_as_float(p<<16); }
__device__ __forceinline__ float bhi(u32 p){ return __uint_as_float(p & 0xffff0000u); }

// ---------------- edge partition into dst-buckets ----------------
// packed edge word: (dst & 63) << 17 | src   (src < 2^17)

__global__ void part_k(const int* __restrict__ src, const int* __restrict__ dst,
                       int* __restrict__ bcnt, u32* __restrict__ elist, int E){
  int i = blockIdx.x*256 + threadIdx.x;
  if (i < E){
    int d = dst[i];
    int b = d >> BSH;
    int p = atomicAdd(&bcnt[b], 1);
    if (p < BCAP)
      elist[(size_t)b*BCAP + p] = ((u32)(d & (BNODES-1)) << 17) | (u32)src[i];
  }
}

// ---------------- per-bucket counting sort -> in-place CSR ----------------
// int LDS atomics only (hardware ds_add_u32 — float LDS atomics are CAS-loop poison).

__global__ __launch_bounds__(256) void csr_k(u32* __restrict__ elist,
    const int* __restrict__ bcnt, int* __restrict__ offs, int* __restrict__ degs,
    float* __restrict__ invd, int M){
  __shared__ int hist[BNODES];
  __shared__ int pos[BNODES];
  __shared__ u32 buf[BCAP];
  __shared__ u32 buf2[BCAP];
  int b = blockIdx.x, t = threadIdx.x;
  if (t < BNODES) hist[t] = 0;
  __syncthreads();
  int cnt = bcnt[b]; if (cnt > BCAP) cnt = BCAP;
  u32* el = elist + (size_t)b*BCAP;
  for (int e = t; e < cnt; e += 256){
    u32 w = el[e];
    buf[e] = w;
    atomicAdd(&hist[w>>17], 1);
  }
  __syncthreads();
  if (t < BNODES){                      // single-wave exclusive scan
    int v = hist[t];
    int s = v;
    for (int off = 1; off < BNODES; off <<= 1){
      int x = __shfl_up(s, off);
      if (t >= off) s += x;
    }
    int excl = s - v;
    pos[t] = excl;
    int node = b*BNODES + t;
    if (node < M){
      offs[node] = b*BCAP + excl;
      degs[node] = v;
      invd[node] = 1.f / fmaxf((float)v, 1.f);
    }
  }
  __syncthreads();
  for (int e = t; e < cnt; e += 256){
    u32 w = buf[e];
    int p = atomicAdd(&pos[w>>17], 1);
    buf2[p] = w & 0x1FFFFu;             // keep src only
  }
  __syncthreads();
  for (int e = t; e < cnt; e += 256) el[e] = buf2[e];   // coalesced write-back
}

// ---------------- dtype conversion ----------------

__global__ void convf_k(const float* __restrict__ in, u16* __restrict__ o, int n4){
  int i = blockIdx.x*256 + threadIdx.x;
  if (i < n4){
    float4 x = ((const float4*)in)[i];
    ushort4 r;
    r.x = f2b(x.x); r.y = f2b(x.y); r.z = f2b(x.z); r.w = f2b(x.w);
    ((ushort4*)o)[i] = r;
  }
}

// W[K][N] row-major -> Wt[N][K] bf16
__global__ void convw_k(const float* __restrict__ W, u16* __restrict__ Wt, int Kd, int Nd){
  int i = blockIdx.x*256 + threadIdx.x;
  if (i < Kd*Nd){
    int k = i / Nd, nn = i - k*Nd;
    Wt[nn*Kd + k] = f2b(W[i]);
  }
}

// ---------------- GEMM: y[M x N] = h[M x 128] * W  (Wt is [N][128] bf16) ----------------

template<int NT>
__global__ __launch_bounds__(256) void gemm_k(const u16* __restrict__ h,
                                              const u16* __restrict__ Wt,
                                              u16* __restrict__ y, int M){
  const int K = FEATS;
  const int N = NT*16;
  int lane = threadIdx.x & 63;
  int wave = threadIdx.x >> 6;
  int m    = lane & 15;
  int quad = lane >> 4;
  int row0 = (blockIdx.x*4 + wave)*16;
  if (row0 >= M) return;
  int rowA = row0 + m; if (rowA > M-1) rowA = M-1;
  const u16* pa = h + (size_t)rowA*K + quad*8;

  f32x4 acc[NT];
  #pragma unroll
  for (int j=0;j<NT;++j) acc[j] = (f32x4){0.f,0.f,0.f,0.f};

  #pragma unroll
  for (int kk=0; kk<K; kk+=32){
    short8 a = *(const short8*)(pa + kk);
    #pragma unroll
    for (int j=0;j<NT;++j){
      short8 b = *(const short8*)(Wt + (size_t)(j*16 + m)*K + kk + quad*8);
      acc[j] = __builtin_amdgcn_mfma_f32_16x16x32_bf16(a, b, acc[j], 0, 0, 0);
    }
  }

  #pragma unroll
  for (int j=0;j<NT;++j){
    #pragma unroll
    for (int r=0;r<4;++r){
      int row = row0 + quad*4 + r;                  // C/D: row = quad*4 + reg
      if (row < M) y[(size_t)row*N + j*16 + m] = f2b(acc[j][r]);  // col = lane&15
    }
  }
}

// ---------------- 128-feat aggregation (layers 0..2) ----------------
// one wave per node, register accumulation, 4 gathers in flight.

__global__ __launch_bounds__(256) void aggL2_k(const u32* __restrict__ y2,
    const u32* __restrict__ el, const int* __restrict__ offs,
    const int* __restrict__ degs, const float* __restrict__ invd,
    const float* __restrict__ bias, const float* __restrict__ epsv, int ei,
    u32* __restrict__ hout, int M){
  int lane = threadIdx.x & 63;
  int v = blockIdx.x*4 + (threadIdx.x >> 6);
  if (v >= M) return;
  int start = offs[v], deg = degs[v], end = start + deg;
  float a0 = 0.f, a1 = 0.f;
  for (int base = start; base < end; base += 64){
    int nn = end - base; if (nn > 64) nn = 64;
    int my = (base + lane < end) ? (int)el[base + lane] : 0;
    int j = 0;
    for (; j + 4 <= nn; j += 4){
      int s0 = __shfl(my, j),   s1 = __shfl(my, j+1);
      int s2 = __shfl(my, j+2), s3 = __shfl(my, j+3);
      u32 p0 = y2[(size_t)s0*64 + lane];
      u32 p1 = y2[(size_t)s1*64 + lane];
      u32 p2 = y2[(size_t)s2*64 + lane];
      u32 p3 = y2[(size_t)s3*64 + lane];
      a0 += blo(p0) + blo(p1) + blo(p2) + blo(p3);
      a1 += bhi(p0) + bhi(p1) + bhi(p2) + bhi(p3);
    }
    for (; j < nn; ++j){
      int s = __shfl(my, j);
      u32 p = y2[(size_t)s*64 + lane];
      a0 += blo(p); a1 += bhi(p);
    }
  }
  u32 pv = y2[(size_t)v*64 + lane];
  float inv = invd[v], e1s = 1.f + epsv[ei];
  float o0 = e1s*blo(pv) + inv*a0 + bias[lane*2];
  float o1 = e1s*bhi(pv) + inv*a1 + bias[lane*2+1];
  o0 = fmaxf(o0, 0.f); o1 = fmaxf(o1, 0.f);
  hout[(size_t)v*64 + lane] = (u32)f2b(o0) | ((u32)f2b(o1) << 16);
}

// ---------------- final 16-feat aggregation, f32 out, no relu ----------------
// one wave per node; 4 sub-groups of 16 lanes each take every 4th edge.

__global__ __launch_bounds__(256) void aggF2_k(const u16* __restrict__ y,
    const u32* __restrict__ el, const int* __restrict__ offs,
    const int* __restrict__ degs, const float* __restrict__ invd,
    const float* __restrict__ bias, const float* __restrict__ epsv,
    float* __restrict__ out, int M){
  int lane = threadIdx.x & 63;
  int v = blockIdx.x*4 + (threadIdx.x >> 6);
  if (v >= M) return;
  int f = lane & 15, sub = lane >> 4;
  int start = offs[v], end = start + degs[v];
  float acc = 0.f;
  for (int e = start + sub; e < end; e += 4){
    u32 s = el[e];
    acc += b2f(y[(size_t)s*NCLS + f]);
  }
  acc += __shfl_xor(acc, 16);
  acc += __shfl_xor(acc, 32);
  if (sub == 0){
    float o = (1.f + epsv[3])*b2f(y[(size_t)v*NCLS + f]) + invd[v]*acc + bias[f];
    out[(size_t)v*NCLS + f] = o;
  }
}

// ---------------- launch ----------------

extern "C" void kernel_launch(void* const* d_in, const int* in_sizes, int n_in,
                              void* d_out, int out_size, void* d_ws, size_t ws_size,
                              hipStream_t stream){
  const float* feats = (const float*)d_in[0];
  const int*   src   = (const int*)d_in[1];
  const int*   dst   = (const int*)d_in[2];
  const float* W0 = (const float*)d_in[3];  const float* b0 = (const float*)d_in[4];
  const float* W1 = (const float*)d_in[5];  const float* b1 = (const float*)d_in[6];
  const float* W2 = (const float*)d_in[7];  const float* b2 = (const float*)d_in[8];
  const float* W3 = (const float*)d_in[9];  const float* b3 = (const float*)d_in[10];
  const float* eps = (const float*)d_in[11];

  char* w = (char*)d_ws;
  auto alloc = [&](size_t bytes)->char*{
    char* p = w; w += (bytes + 255) & ~(size_t)255; return p;
  };
  int*  bcnt  = (int*)alloc(sizeof(int)*NB);
  int*  offs  = (int*)alloc(sizeof(int)*NODES);
  int*  degs  = (int*)alloc(sizeof(int)*NODES);
  float* invd = (float*)alloc(sizeof(float)*NODES);
  u32*  elist = (u32*)alloc(sizeof(u32)*(size_t)NB*BCAP);
  u16*  hb    = (u16*)alloc(sizeof(u16)*(size_t)NODES*FEATS);
  u16*  yb    = (u16*)alloc(sizeof(u16)*(size_t)NODES*FEATS);
  u16*  Wt0   = (u16*)alloc(sizeof(u16)*128*128);
  u16*  Wt1   = (u16*)alloc(sizeof(u16)*128*128);
  u16*  Wt2   = (u16*)alloc(sizeof(u16)*128*128);
  u16*  Wt3   = (u16*)alloc(sizeof(u16)*16*128);

  // ---- bucket partition + per-bucket counting sort -> CSR ----
  hipMemsetAsync(bcnt, 0, sizeof(int)*NB, stream);
  part_k<<<(EDGES+255)/256, 256, 0, stream>>>(src, dst, bcnt, elist, EDGES);
  csr_k<<<NB, 256, 0, stream>>>(elist, bcnt, offs, degs, invd, NODES);

  // ---- convert inputs to bf16 ----
  convf_k<<<((NODES*FEATS/4)+255)/256, 256, 0, stream>>>(feats, hb, NODES*FEATS/4);
  convw_k<<<(128*128+255)/256, 256, 0, stream>>>(W0, Wt0, 128, 128);
  convw_k<<<(128*128+255)/256, 256, 0, stream>>>(W1, Wt1, 128, 128);
  convw_k<<<(128*128+255)/256, 256, 0, stream>>>(W2, Wt2, 128, 128);
  convw_k<<<(128*16 +255)/256, 256, 0, stream>>>(W3, Wt3, 128, 16);

  int gblocks = (NODES + 63)/64;
  int ablocks = (NODES + 3)/4;

  // layers 0..2: y = h@W ; h = relu((1+eps)y + mean_agg(y) + b)
  gemm_k<8><<<gblocks, 256, 0, stream>>>(hb, Wt0, yb, NODES);
  aggL2_k<<<ablocks, 256, 0, stream>>>((const u32*)yb, elist, offs, degs, invd, b0, eps, 0, (u32*)hb, NODES);
  gemm_k<8><<<gblocks, 256, 0, stream>>>(hb, Wt1, yb, NODES);
  aggL2_k<<<ablocks, 256, 0, stream>>>((const u32*)yb, elist, offs, degs, invd, b1, eps, 1, (u32*)hb, NODES);
  gemm_k<8><<<gblocks, 256, 0, stream>>>(hb, Wt2, yb, NODES);
  aggL2_k<<<ablocks, 256, 0, stream>>>((const u32*)yb, elist, offs, degs, invd, b2, eps, 2, (u32*)hb, NODES);

  // layer 3: y = h@W3 (N=16); out = (1+eps)y + mean_agg(y) + b  (f32, no relu)
  gemm_k<1><<<gblocks, 256, 0, stream>>>(hb, Wt3, yb, NODES);
  aggF2_k<<<ablocks, 256, 0, stream>>>(yb, elist, offs, degs, invd, b3, eps, (float*)d_out, NODES);
}

// Round 4
// 599.402 us; speedup vs baseline: 6.9307x; 1.2159x over previous
//
#include <hip/hip_runtime.h>

#define NODES 100000
#define EDGES 1600000
#define FEATS 128
#define NCLS  16

// bucket = 64 consecutive dst nodes
#define BSH    6
#define BNODES 64
#define NB     ((NODES + BNODES - 1) / BNODES)   // 1563
#define CHUNK  32768
#define NBLK   ((EDGES + CHUNK - 1) / CHUNK)     // 49
#define NHIST  (NB * NBLK)                       // 76587
#define BCAP   2048                              // per-bucket LDS sort capacity

typedef unsigned int  u32;
typedef unsigned short u16;
typedef __attribute__((ext_vector_type(8))) short short8;
typedef __attribute__((ext_vector_type(4))) float f32x4;

__device__ __forceinline__ float b2f(u16 v){ return __uint_as_float(((u32)v)<<16); }
__device__ __forceinline__ u16 f2b(float f){
  u32 u = __float_as_uint(f);
  u += 0x7fffu + ((u>>16)&1u);   // RNE
  return (u16)(u>>16);
}
__device__ __forceinline__ float blo(u32 p){ return __uint_as_float(p<<16); }
__device__ __forceinline__ float bhi(u32 p){ return __uint_as_float(p & 0xffff0000u); }

// ---------------- phase A: per-chunk bucket histogram ----------------

__global__ __launch_bounds__(256) void pA_k(const int* __restrict__ dst,
                                            int* __restrict__ gh, int E){
  __shared__ int hist[NB];
  int t = threadIdx.x, blk = blockIdx.x;
  for (int j = t; j < NB; j += 256) hist[j] = 0;
  __syncthreads();
  int e0 = blk*CHUNK, e1 = e0 + CHUNK; if (e1 > E) e1 = E;
  for (int e = e0 + t; e < e1; e += 256) atomicAdd(&hist[dst[e] >> BSH], 1);
  __syncthreads();
  for (int j = t; j < NB; j += 256) gh[j*NBLK + blk] = hist[j];
}

// ---------------- phase B: exclusive scan of gh (76587 elems) ----------------

__global__ __launch_bounds__(256) void scan1_k(const int* __restrict__ in, int* __restrict__ out,
                                               int* __restrict__ bsum, int n){
  __shared__ int sh[256];
  int t = threadIdx.x;
  int base = blockIdx.x*2048 + t*8;
  int v[8]; int s = 0;
  #pragma unroll
  for (int j=0;j<8;++j) v[j] = (base+j < n) ? in[base+j] : 0;
  #pragma unroll
  for (int j=0;j<8;++j){ int tmp = v[j]; v[j] = s; s += tmp; }
  sh[t] = s; __syncthreads();
  for (int off=1; off<256; off<<=1){
    int x = (t>=off) ? sh[t-off] : 0;
    __syncthreads();
    sh[t] += x;
    __syncthreads();
  }
  int excl = sh[t] - s;
  #pragma unroll
  for (int j=0;j<8;++j) if (base+j < n) out[base+j] = excl + v[j];
  if (t == 255) bsum[blockIdx.x] = sh[255];
}

__global__ void scan2_k(const int* __restrict__ bsum, int* __restrict__ boff, int nb){
  int lane = threadIdx.x;           // single wave, nb <= 64
  int orig = (lane < nb) ? bsum[lane] : 0;
  int v = orig;
  for (int off=1; off<64; off<<=1){
    int x = __shfl_up(v, off);
    if (lane >= off) v += x;
  }
  if (lane < nb) boff[lane] = v - orig;
}

__global__ void scan3_k(int* __restrict__ gscan, const int* __restrict__ boff,
                        int* __restrict__ bstart, int n){
  int i = blockIdx.x*256 + threadIdx.x;
  if (i < n){
    int v = gscan[i] + boff[i>>11];
    gscan[i] = v;
    if (i % NBLK == 0) bstart[i / NBLK] = v;
    if (i == 0) bstart[NB] = EDGES;
  }
}

// ---------------- phase C: scatter to exact final slots ----------------
// packed word: (dst & 63) << 17 | src

__global__ __launch_bounds__(256) void pC_k(const int* __restrict__ src,
    const int* __restrict__ dst, const int* __restrict__ gscan,
    u32* __restrict__ elist, int E){
  __shared__ int pos[NB];
  int t = threadIdx.x, blk = blockIdx.x;
  for (int j = t; j < NB; j += 256) pos[j] = gscan[j*NBLK + blk];
  __syncthreads();
  int e0 = blk*CHUNK, e1 = e0 + CHUNK; if (e1 > E) e1 = E;
  for (int e = e0 + t; e < e1; e += 256){
    int d = dst[e];
    int b = d >> BSH;
    int p = atomicAdd(&pos[b], 1);
    elist[p] = ((u32)(d & (BNODES-1)) << 17) | (u32)src[e];
  }
}

// ---------------- per-bucket counting sort (in place) + degrees ----------------

__global__ __launch_bounds__(256) void csr_k(u32* __restrict__ elist,
    const int* __restrict__ bstart, int* __restrict__ offs, int* __restrict__ degs,
    float* __restrict__ invd, int M){
  __shared__ int hist[BNODES];
  __shared__ int pos[BNODES];
  __shared__ u32 buf[BCAP];
  __shared__ u32 buf2[BCAP];
  int b = blockIdx.x, t = threadIdx.x;
  if (t < BNODES) hist[t] = 0;
  __syncthreads();
  int s0 = bstart[b];
  int cnt = bstart[b+1] - s0; if (cnt > BCAP) cnt = BCAP;
  u32* el = elist + s0;
  for (int e = t; e < cnt; e += 256){
    u32 w = el[e];
    buf[e] = w;
    atomicAdd(&hist[w>>17], 1);
  }
  __syncthreads();
  if (t < BNODES){                      // single-wave exclusive scan
    int v = hist[t];
    int s = v;
    for (int off = 1; off < BNODES; off <<= 1){
      int x = __shfl_up(s, off);
      if (t >= off) s += x;
    }
    int excl = s - v;
    pos[t] = excl;
    int node = b*BNODES + t;
    if (node < M){
      offs[node] = s0 + excl;
      degs[node] = v;
      invd[node] = 1.f / fmaxf((float)v, 1.f);
    }
  }
  __syncthreads();
  for (int e = t; e < cnt; e += 256){
    u32 w = buf[e];
    int p = atomicAdd(&pos[w>>17], 1);
    buf2[p] = w & 0x1FFFFu;             // keep src only
  }
  __syncthreads();
  for (int e = t; e < cnt; e += 256) el[e] = buf2[e];   // coalesced write-back
}

// ---------------- dtype conversion ----------------

__global__ void convf_k(const float* __restrict__ in, u16* __restrict__ o, int n4){
  int i = blockIdx.x*256 + threadIdx.x;
  if (i < n4){
    float4 x = ((const float4*)in)[i];
    ushort4 r;
    r.x = f2b(x.x); r.y = f2b(x.y); r.z = f2b(x.z); r.w = f2b(x.w);
    ((ushort4*)o)[i] = r;
  }
}

// W[K][N] row-major -> Wt[N][K] bf16
__global__ void convw_k(const float* __restrict__ W, u16* __restrict__ Wt, int Kd, int Nd){
  int i = blockIdx.x*256 + threadIdx.x;
  if (i < Kd*Nd){
    int k = i / Nd, nn = i - k*Nd;
    Wt[nn*Kd + k] = f2b(W[i]);
  }
}

// ---------------- GEMM: y[M x N] = h[M x 128] * W  (Wt is [N][128] bf16) ----------------

template<int NT>
__global__ __launch_bounds__(256) void gemm_k(const u16* __restrict__ h,
                                              const u16* __restrict__ Wt,
                                              u16* __restrict__ y, int M){
  const int K = FEATS;
  const int N = NT*16;
  int lane = threadIdx.x & 63;
  int wave = threadIdx.x >> 6;
  int m    = lane & 15;
  int quad = lane >> 4;
  int row0 = (blockIdx.x*4 + wave)*16;
  if (row0 >= M) return;
  int rowA = row0 + m; if (rowA > M-1) rowA = M-1;
  const u16* pa = h + (size_t)rowA*K + quad*8;

  f32x4 acc[NT];
  #pragma unroll
  for (int j=0;j<NT;++j) acc[j] = (f32x4){0.f,0.f,0.f,0.f};

  #pragma unroll
  for (int kk=0; kk<K; kk+=32){
    short8 a = *(const short8*)(pa + kk);
    #pragma unroll
    for (int j=0;j<NT;++j){
      short8 b = *(const short8*)(Wt + (size_t)(j*16 + m)*K + kk + quad*8);
      acc[j] = __builtin_amdgcn_mfma_f32_16x16x32_bf16(a, b, acc[j], 0, 0, 0);
    }
  }

  #pragma unroll
  for (int j=0;j<NT;++j){
    #pragma unroll
    for (int r=0;r<4;++r){
      int row = row0 + quad*4 + r;                  // C/D: row = quad*4 + reg
      if (row < M) y[(size_t)row*N + j*16 + m] = f2b(acc[j][r]);  // col = lane&15
    }
  }
}

// ---------------- 128-feat aggregation (layers 0..2) ----------------
// one wave per node, register accumulation, 8 gathers in flight.

__global__ __launch_bounds__(256) void aggL2_k(const u32* __restrict__ y2,
    const u32* __restrict__ el, const int* __restrict__ offs,
    const int* __restrict__ degs, const float* __restrict__ invd,
    const float* __restrict__ bias, const float* __restrict__ epsv, int ei,
    u32* __restrict__ hout, int M){
  int lane = threadIdx.x & 63;
  int v = blockIdx.x*4 + (threadIdx.x >> 6);
  if (v >= M) return;
  int start = offs[v], deg = degs[v], end = start + deg;
  float a0 = 0.f, a1 = 0.f;
  for (int base = start; base < end; base += 64){
    int nn = end - base; if (nn > 64) nn = 64;
    int my = (base + lane < end) ? (int)el[base + lane] : 0;
    int j = 0;
    for (; j + 8 <= nn; j += 8){
      int s0 = __shfl(my, j),   s1 = __shfl(my, j+1);
      int s2 = __shfl(my, j+2), s3 = __shfl(my, j+3);
      int s4 = __shfl(my, j+4), s5 = __shfl(my, j+5);
      int s6 = __shfl(my, j+6), s7 = __shfl(my, j+7);
      u32 p0 = y2[(size_t)s0*64 + lane];
      u32 p1 = y2[(size_t)s1*64 + lane];
      u32 p2 = y2[(size_t)s2*64 + lane];
      u32 p3 = y2[(size_t)s3*64 + lane];
      u32 p4 = y2[(size_t)s4*64 + lane];
      u32 p5 = y2[(size_t)s5*64 + lane];
      u32 p6 = y2[(size_t)s6*64 + lane];
      u32 p7 = y2[(size_t)s7*64 + lane];
      a0 += blo(p0) + blo(p1) + blo(p2) + blo(p3) + blo(p4) + blo(p5) + blo(p6) + blo(p7);
      a1 += bhi(p0) + bhi(p1) + bhi(p2) + bhi(p3) + bhi(p4) + bhi(p5) + bhi(p6) + bhi(p7);
    }
    for (; j < nn; ++j){
      int s = __shfl(my, j);
      u32 p = y2[(size_t)s*64 + lane];
      a0 += blo(p); a1 += bhi(p);
    }
  }
  u32 pv = y2[(size_t)v*64 + lane];
  float inv = invd[v], e1s = 1.f + epsv[ei];
  float o0 = e1s*blo(pv) + inv*a0 + bias[lane*2];
  float o1 = e1s*bhi(pv) + inv*a1 + bias[lane*2+1];
  o0 = fmaxf(o0, 0.f); o1 = fmaxf(o1, 0.f);
  hout[(size_t)v*64 + lane] = (u32)f2b(o0) | ((u32)f2b(o1) << 16);
}

// ---------------- final 16-feat aggregation, f32 out, no relu ----------------

__global__ __launch_bounds__(256) void aggF2_k(const u16* __restrict__ y,
    const u32* __restrict__ el, const int* __restrict__ offs,
    const int* __restrict__ degs, const float* __restrict__ invd,
    const float* __restrict__ bias, const float* __restrict__ epsv,
    float* __restrict__ out, int M){
  int lane = threadIdx.x & 63;
  int v = blockIdx.x*4 + (threadIdx.x >> 6);
  if (v >= M) return;
  int f = lane & 15, sub = lane >> 4;
  int start = offs[v], end = start + degs[v];
  float acc = 0.f;
  for (int e = start + sub; e < end; e += 4){
    u32 s = el[e];
    acc += b2f(y[(size_t)s*NCLS + f]);
  }
  acc += __shfl_xor(acc, 16);
  acc += __shfl_xor(acc, 32);
  if (sub == 0){
    float o = (1.f + epsv[3])*b2f(y[(size_t)v*NCLS + f]) + invd[v]*acc + bias[f];
    out[(size_t)v*NCLS + f] = o;
  }
}

// ---------------- launch ----------------

extern "C" void kernel_launch(void* const* d_in, const int* in_sizes, int n_in,
                              void* d_out, int out_size, void* d_ws, size_t ws_size,
                              hipStream_t stream){
  const float* feats = (const float*)d_in[0];
  const int*   src   = (const int*)d_in[1];
  const int*   dst   = (const int*)d_in[2];
  const float* W0 = (const float*)d_in[3];  const float* b0 = (const float*)d_in[4];
  const float* W1 = (const float*)d_in[5];  const float* b1 = (const float*)d_in[6];
  const float* W2 = (const float*)d_in[7];  const float* b2 = (const float*)d_in[8];
  const float* W3 = (const float*)d_in[9];  const float* b3 = (const float*)d_in[10];
  const float* eps = (const float*)d_in[11];

  char* w = (char*)d_ws;
  auto alloc = [&](size_t bytes)->char*{
    char* p = w; w += (bytes + 255) & ~(size_t)255; return p;
  };
  int*  gh    = (int*)alloc(sizeof(int)*NHIST);
  int*  gscan = (int*)alloc(sizeof(int)*NHIST);
  int*  bsum  = (int*)alloc(sizeof(int)*64);
  int*  boff  = (int*)alloc(sizeof(int)*64);
  int*  bstart= (int*)alloc(sizeof(int)*(NB+1));
  int*  offs  = (int*)alloc(sizeof(int)*NODES);
  int*  degs  = (int*)alloc(sizeof(int)*NODES);
  float* invd = (float*)alloc(sizeof(float)*NODES);
  u32*  elist = (u32*)alloc(sizeof(u32)*EDGES);
  u16*  hb    = (u16*)alloc(sizeof(u16)*(size_t)NODES*FEATS);
  u16*  yb    = (u16*)alloc(sizeof(u16)*(size_t)NODES*FEATS);
  u16*  Wt0   = (u16*)alloc(sizeof(u16)*128*128);
  u16*  Wt1   = (u16*)alloc(sizeof(u16)*128*128);
  u16*  Wt2   = (u16*)alloc(sizeof(u16)*128*128);
  u16*  Wt3   = (u16*)alloc(sizeof(u16)*16*128);

  // ---- deterministic 3-phase partition -> dense bucketed elist ----
  pA_k<<<NBLK, 256, 0, stream>>>(dst, gh, EDGES);
  int snb = (NHIST + 2047)/2048;                 // 38
  scan1_k<<<snb, 256, 0, stream>>>(gh, gscan, bsum, NHIST);
  scan2_k<<<1, 64, 0, stream>>>(bsum, boff, snb);
  scan3_k<<<(NHIST+255)/256, 256, 0, stream>>>(gscan, boff, bstart, NHIST);
  pC_k<<<NBLK, 256, 0, stream>>>(src, dst, gscan, elist, EDGES);
  csr_k<<<NB, 256, 0, stream>>>(elist, bstart, offs, degs, invd, NODES);

  // ---- convert inputs to bf16 ----
  convf_k<<<((NODES*FEATS/4)+255)/256, 256, 0, stream>>>(feats, hb, NODES*FEATS/4);
  convw_k<<<(128*128+255)/256, 256, 0, stream>>>(W0, Wt0, 128, 128);
  convw_k<<<(128*128+255)/256, 256, 0, stream>>>(W1, Wt1, 128, 128);
  convw_k<<<(128*128+255)/256, 256, 0, stream>>>(W2, Wt2, 128, 128);
  convw_k<<<(128*16 +255)/256, 256, 0, stream>>>(W3, Wt3, 128, 16);

  int gblocks = (NODES + 63)/64;
  int ablocks = (NODES + 3)/4;

  // layers 0..2: y = h@W ; h = relu((1+eps)y + mean_agg(y) + b)
  gemm_k<8><<<gblocks, 256, 0, stream>>>(hb, Wt0, yb, NODES);
  aggL2_k<<<ablocks, 256, 0, stream>>>((const u32*)yb, elist, offs, degs, invd, b0, eps, 0, (u32*)hb, NODES);
  gemm_k<8><<<gblocks, 256, 0, stream>>>(hb, Wt1, yb, NODES);
  aggL2_k<<<ablocks, 256, 0, stream>>>((const u32*)yb, elist, offs, degs, invd, b1, eps, 1, (u32*)hb, NODES);
  gemm_k<8><<<gblocks, 256, 0, stream>>>(hb, Wt2, yb, NODES);
  aggL2_k<<<ablocks, 256, 0, stream>>>((const u32*)yb, elist, offs, degs, invd, b2, eps, 2, (u32*)hb, NODES);

  // layer 3: y = h@W3 (N=16); out = (1+eps)y + mean_agg(y) + b  (f32, no relu)
  gemm_k<1><<<gblocks, 256, 0, stream>>>(hb, Wt3, yb, NODES);
  aggF2_k<<<ablocks, 256, 0, stream>>>(yb, elist, offs, degs, invd, b3, eps, (float*)d_out, NODES);
}

// Round 5
// 540.770 us; speedup vs baseline: 7.6821x; 1.1084x over previous
//
#include <hip/hip_runtime.h>

#define NODES 100000
#define EDGES 1600000
#define FEATS 128
#define NCLS  16

// bucket = 64 consecutive dst nodes
#define BSH    6
#define BNODES 64
#define NB     ((NODES + BNODES - 1) / BNODES)   // 1563
#define CHUNK  8192
#define NBLK   ((EDGES + CHUNK - 1) / CHUNK)     // 196
#define NHIST  (NB * NBLK)                       // 306348
#define BCAP   2048                              // per-bucket LDS sort capacity

typedef unsigned int  u32;
typedef unsigned short u16;
typedef __attribute__((ext_vector_type(8))) short short8;
typedef __attribute__((ext_vector_type(4))) float f32x4;

__device__ __forceinline__ float b2f(u16 v){ return __uint_as_float(((u32)v)<<16); }
__device__ __forceinline__ u16 f2b(float f){
  u32 u = __float_as_uint(f);
  u += 0x7fffu + ((u>>16)&1u);   // RNE
  return (u16)(u>>16);
}
__device__ __forceinline__ float blo(u32 p){ return __uint_as_float(p<<16); }
__device__ __forceinline__ float bhi(u32 p){ return __uint_as_float(p & 0xffff0000u); }

// ---------------- phase A: per-chunk bucket histogram ----------------

__global__ __launch_bounds__(256) void pA_k(const int* __restrict__ dst,
                                            int* __restrict__ gh, int E){
  __shared__ int hist[NB];
  int t = threadIdx.x, blk = blockIdx.x;
  for (int j = t; j < NB; j += 256) hist[j] = 0;
  __syncthreads();
  int e0 = blk*CHUNK, e1 = e0 + CHUNK; if (e1 > E) e1 = E;
  for (int e = e0 + t; e < e1; e += 256) atomicAdd(&hist[dst[e] >> BSH], 1);
  __syncthreads();
  for (int j = t; j < NB; j += 256) gh[j*NBLK + blk] = hist[j];
}

// ---------------- phase B: exclusive scan of gh ----------------

__global__ __launch_bounds__(256) void scan1_k(const int* __restrict__ in, int* __restrict__ out,
                                               int* __restrict__ bsum, int n){
  __shared__ int sh[256];
  int t = threadIdx.x;
  int base = blockIdx.x*2048 + t*8;
  int v[8]; int s = 0;
  #pragma unroll
  for (int j=0;j<8;++j) v[j] = (base+j < n) ? in[base+j] : 0;
  #pragma unroll
  for (int j=0;j<8;++j){ int tmp = v[j]; v[j] = s; s += tmp; }
  sh[t] = s; __syncthreads();
  for (int off=1; off<256; off<<=1){
    int x = (t>=off) ? sh[t-off] : 0;
    __syncthreads();
    sh[t] += x;
    __syncthreads();
  }
  int excl = sh[t] - s;
  #pragma unroll
  for (int j=0;j<8;++j) if (base+j < n) out[base+j] = excl + v[j];
  if (t == 255) bsum[blockIdx.x] = sh[255];
}

// 256-entry block scan (nb <= 256)
__global__ __launch_bounds__(256) void scan2_k(const int* __restrict__ bsum,
                                               int* __restrict__ boff, int nb){
  __shared__ int sh[256];
  int t = threadIdx.x;
  int v = (t < nb) ? bsum[t] : 0;
  sh[t] = v; __syncthreads();
  for (int off=1; off<256; off<<=1){
    int x = (t>=off) ? sh[t-off] : 0;
    __syncthreads();
    sh[t] += x;
    __syncthreads();
  }
  if (t < nb) boff[t] = sh[t] - v;
}

__global__ void scan3_k(int* __restrict__ gscan, const int* __restrict__ boff,
                        int* __restrict__ bstart, int n){
  int i = blockIdx.x*256 + threadIdx.x;
  if (i < n){
    int v = gscan[i] + boff[i>>11];
    gscan[i] = v;
    if (i % NBLK == 0) bstart[i / NBLK] = v;
    if (i == 0) bstart[NB] = EDGES;
  }
}

// ---------------- phase C: LDS counting sort, then streamed coalesced write ----------------
// packed word: (dst & 63) << 17 | src

__global__ __launch_bounds__(256) void pC_k(const int* __restrict__ src,
    const int* __restrict__ dst, const int* __restrict__ gscan,
    u32* __restrict__ elist, int E){
  __shared__ int A[NB];        // hist -> excl -> delta
  __shared__ int B[NB];        // running local position (starts at excl)
  __shared__ int sp[256];      // scan partials
  __shared__ u32 pay[CHUNK];   // payload by local sorted index
  __shared__ u16 bkt[CHUNK];   // bucket by local sorted index
  int t = threadIdx.x, blk = blockIdx.x;
  for (int j = t; j < NB; j += 256) A[j] = 0;
  __syncthreads();
  int e0 = blk*CHUNK, e1 = e0 + CHUNK; if (e1 > E) e1 = E;
  int cnt = e1 - e0;
  for (int e = e0 + t; e < e1; e += 256) atomicAdd(&A[dst[e] >> BSH], 1);
  __syncthreads();
  // block-exclusive scan over A[0..NB): 7 elems/thread
  {
    int base = t*7;
    int cv[7]; int s = 0;
    #pragma unroll
    for (int j=0;j<7;++j){ int idx = base+j; cv[j] = (idx < NB) ? A[idx] : 0; s += cv[j]; }
    sp[t] = s; __syncthreads();
    for (int off=1; off<256; off<<=1){
      int x = (t>=off) ? sp[t-off] : 0;
      __syncthreads();
      sp[t] += x;
      __syncthreads();
    }
    int run = sp[t] - s;
    #pragma unroll
    for (int j=0;j<7;++j){
      int idx = base+j;
      if (idx < NB){ A[idx] = run; B[idx] = run; run += cv[j]; }
    }
  }
  __syncthreads();
  // delta[b] = global run start - local excl
  for (int j = t; j < NB; j += 256) A[j] = gscan[j*NBLK + blk] - A[j];
  __syncthreads();
  // placement into LDS sorted order
  for (int e = e0 + t; e < e1; e += 256){
    int d = dst[e];
    int b = d >> BSH;
    u32 w = ((u32)(d & (BNODES-1)) << 17) | (u32)src[e];
    int r = atomicAdd(&B[b], 1);
    pay[r] = w; bkt[r] = (u16)b;
  }
  __syncthreads();
  // streamed write: consecutive i -> consecutive global slots within runs
  for (int i = t; i < cnt; i += 256){
    int b = bkt[i];
    elist[i + A[b]] = pay[i];
  }
}

// ---------------- per-bucket counting sort (in place) + degrees ----------------

__global__ __launch_bounds__(256) void csr_k(u32* __restrict__ elist,
    const int* __restrict__ bstart, int* __restrict__ offs, int* __restrict__ degs,
    float* __restrict__ invd, int M){
  __shared__ int hist[BNODES];
  __shared__ int pos[BNODES];
  __shared__ u32 buf[BCAP];
  __shared__ u32 buf2[BCAP];
  int b = blockIdx.x, t = threadIdx.x;
  if (t < BNODES) hist[t] = 0;
  __syncthreads();
  int s0 = bstart[b];
  int cnt = bstart[b+1] - s0; if (cnt > BCAP) cnt = BCAP;
  u32* el = elist + s0;
  for (int e = t; e < cnt; e += 256){
    u32 w = el[e];
    buf[e] = w;
    atomicAdd(&hist[w>>17], 1);
  }
  __syncthreads();
  if (t < BNODES){                      // single-wave exclusive scan
    int v = hist[t];
    int s = v;
    for (int off = 1; off < BNODES; off <<= 1){
      int x = __shfl_up(s, off);
      if (t >= off) s += x;
    }
    int excl = s - v;
    pos[t] = excl;
    int node = b*BNODES + t;
    if (node < M){
      offs[node] = s0 + excl;
      degs[node] = v;
      invd[node] = 1.f / fmaxf((float)v, 1.f);
    }
  }
  __syncthreads();
  for (int e = t; e < cnt; e += 256){
    u32 w = buf[e];
    int p = atomicAdd(&pos[w>>17], 1);
    buf2[p] = w & 0x1FFFFu;             // keep src only
  }
  __syncthreads();
  for (int e = t; e < cnt; e += 256) el[e] = buf2[e];   // coalesced write-back
}

// ---------------- dtype conversion ----------------

__global__ void convf_k(const float* __restrict__ in, u16* __restrict__ o, int n4){
  int i = blockIdx.x*256 + threadIdx.x;
  if (i < n4){
    float4 x = ((const float4*)in)[i];
    ushort4 r;
    r.x = f2b(x.x); r.y = f2b(x.y); r.z = f2b(x.z); r.w = f2b(x.w);
    ((ushort4*)o)[i] = r;
  }
}

// W[K][N] row-major -> Wt[N][K] bf16
__global__ void convw_k(const float* __restrict__ W, u16* __restrict__ Wt, int Kd, int Nd){
  int i = blockIdx.x*256 + threadIdx.x;
  if (i < Kd*Nd){
    int k = i / Nd, nn = i - k*Nd;
    Wt[nn*Kd + k] = f2b(W[i]);
  }
}

// ---------------- GEMM: y[M x N] = h[M x 128] * W  (Wt is [N][128] bf16) ----------------

template<int NT>
__global__ __launch_bounds__(256) void gemm_k(const u16* __restrict__ h,
                                              const u16* __restrict__ Wt,
                                              u16* __restrict__ y, int M){
  const int K = FEATS;
  const int N = NT*16;
  int lane = threadIdx.x & 63;
  int wave = threadIdx.x >> 6;
  int m    = lane & 15;
  int quad = lane >> 4;
  int row0 = (blockIdx.x*4 + wave)*16;
  if (row0 >= M) return;
  int rowA = row0 + m; if (rowA > M-1) rowA = M-1;
  const u16* pa = h + (size_t)rowA*K + quad*8;

  f32x4 acc[NT];
  #pragma unroll
  for (int j=0;j<NT;++j) acc[j] = (f32x4){0.f,0.f,0.f,0.f};

  #pragma unroll
  for (int kk=0; kk<K; kk+=32){
    short8 a = *(const short8*)(pa + kk);
    #pragma unroll
    for (int j=0;j<NT;++j){
      short8 b = *(const short8*)(Wt + (size_t)(j*16 + m)*K + kk + quad*8);
      acc[j] = __builtin_amdgcn_mfma_f32_16x16x32_bf16(a, b, acc[j], 0, 0, 0);
    }
  }

  #pragma unroll
  for (int j=0;j<NT;++j){
    #pragma unroll
    for (int r=0;r<4;++r){
      int row = row0 + quad*4 + r;                  // C/D: row = quad*4 + reg
      if (row < M) y[(size_t)row*N + j*16 + m] = f2b(acc[j][r]);  // col = lane&15
    }
  }
}

// ---------------- 128-feat aggregation (layers 0..2) ----------------
// one wave per node; uint2 gathers: lanes 0-31 cover row s_2j, lanes 32-63 row s_2j+1.
// 8 loads in flight = 16 rows (4 KB). Halves combined via shfl_xor(32).

__global__ __launch_bounds__(256) void aggL2_k(const uint2* __restrict__ y4,
    const u32* __restrict__ el, const int* __restrict__ offs,
    const int* __restrict__ degs, const float* __restrict__ invd,
    const float* __restrict__ bias, const float* __restrict__ epsv, int ei,
    uint2* __restrict__ hout, int M){
  int lane = threadIdx.x & 63;
  int v = blockIdx.x*4 + (threadIdx.x >> 6);
  if (v >= M) return;
  int g = lane >> 5;          // half id (which edge of a pair)
  int c = lane & 31;          // column: features 4c..4c+3
  int start = offs[v], deg = degs[v];
  int npair = deg >> 1;
  float a0=0.f, a1=0.f, a2=0.f, a3=0.f;
  for (int pb = 0; pb < npair; pb += 32){
    int nn = npair - pb; if (nn > 32) nn = 32;
    int my = (lane < 2*nn) ? (int)el[start + 2*pb + lane] : 0;
    int j = 0;
    for (; j + 8 <= nn; j += 8){
      int s0 = __shfl(my, 2*j    + g), s1 = __shfl(my, 2*j+2  + g);
      int s2 = __shfl(my, 2*j+4  + g), s3 = __shfl(my, 2*j+6  + g);
      int s4 = __shfl(my, 2*j+8  + g), s5 = __shfl(my, 2*j+10 + g);
      int s6 = __shfl(my, 2*j+12 + g), s7 = __shfl(my, 2*j+14 + g);
      uint2 p0 = y4[(size_t)s0*32 + c];
      uint2 p1 = y4[(size_t)s1*32 + c];
      uint2 p2 = y4[(size_t)s2*32 + c];
      uint2 p3 = y4[(size_t)s3*32 + c];
      uint2 p4 = y4[(size_t)s4*32 + c];
      uint2 p5 = y4[(size_t)s5*32 + c];
      uint2 p6 = y4[(size_t)s6*32 + c];
      uint2 p7 = y4[(size_t)s7*32 + c];
      a0 += blo(p0.x)+blo(p1.x)+blo(p2.x)+blo(p3.x)+blo(p4.x)+blo(p5.x)+blo(p6.x)+blo(p7.x);
      a1 += bhi(p0.x)+bhi(p1.x)+bhi(p2.x)+bhi(p3.x)+bhi(p4.x)+bhi(p5.x)+bhi(p6.x)+bhi(p7.x);
      a2 += blo(p0.y)+blo(p1.y)+blo(p2.y)+blo(p3.y)+blo(p4.y)+blo(p5.y)+blo(p6.y)+blo(p7.y);
      a3 += bhi(p0.y)+bhi(p1.y)+bhi(p2.y)+bhi(p3.y)+bhi(p4.y)+bhi(p5.y)+bhi(p6.y)+bhi(p7.y);
    }
    for (; j < nn; ++j){
      int s = __shfl(my, 2*j + g);
      uint2 p = y4[(size_t)s*32 + c];
      a0 += blo(p.x); a1 += bhi(p.x); a2 += blo(p.y); a3 += bhi(p.y);
    }
  }
  if (deg & 1){
    int s = (int)el[start + deg - 1];   // wave-uniform load
    uint2 p = y4[(size_t)s*32 + c];
    if (g == 0){ a0 += blo(p.x); a1 += bhi(p.x); a2 += blo(p.y); a3 += bhi(p.y); }
  }
  a0 += __shfl_xor(a0, 32);
  a1 += __shfl_xor(a1, 32);
  a2 += __shfl_xor(a2, 32);
  a3 += __shfl_xor(a3, 32);
  uint2 pv = y4[(size_t)v*32 + c];
  float4 bi = ((const float4*)bias)[c];
  float inv = invd[v], e1s = 1.f + epsv[ei];
  float o0 = fmaxf(e1s*blo(pv.x) + inv*a0 + bi.x, 0.f);
  float o1 = fmaxf(e1s*bhi(pv.x) + inv*a1 + bi.y, 0.f);
  float o2 = fmaxf(e1s*blo(pv.y) + inv*a2 + bi.z, 0.f);
  float o3 = fmaxf(e1s*bhi(pv.y) + inv*a3 + bi.w, 0.f);
  if (g == 0){
    uint2 r;
    r.x = (u32)f2b(o0) | ((u32)f2b(o1) << 16);
    r.y = (u32)f2b(o2) | ((u32)f2b(o3) << 16);
    hout[(size_t)v*32 + c] = r;
  }
}

// ---------------- final 16-feat aggregation, f32 out, no relu ----------------

__global__ __launch_bounds__(256) void aggF2_k(const u16* __restrict__ y,
    const u32* __restrict__ el, const int* __restrict__ offs,
    const int* __restrict__ degs, const float* __restrict__ invd,
    const float* __restrict__ bias, const float* __restrict__ epsv,
    float* __restrict__ out, int M){
  int lane = threadIdx.x & 63;
  int v = blockIdx.x*4 + (threadIdx.x >> 6);
  if (v >= M) return;
  int f = lane & 15, sub = lane >> 4;
  int start = offs[v], end = start + degs[v];
  float acc = 0.f;
  for (int e = start + sub; e < end; e += 4){
    u32 s = el[e];
    acc += b2f(y[(size_t)s*NCLS + f]);
  }
  acc += __shfl_xor(acc, 16);
  acc += __shfl_xor(acc, 32);
  if (sub == 0){
    float o = (1.f + epsv[3])*b2f(y[(size_t)v*NCLS + f]) + invd[v]*acc + bias[f];
    out[(size_t)v*NCLS + f] = o;
  }
}

// ---------------- launch ----------------

extern "C" void kernel_launch(void* const* d_in, const int* in_sizes, int n_in,
                              void* d_out, int out_size, void* d_ws, size_t ws_size,
                              hipStream_t stream){
  const float* feats = (const float*)d_in[0];
  const int*   src   = (const int*)d_in[1];
  const int*   dst   = (const int*)d_in[2];
  const float* W0 = (const float*)d_in[3];  const float* b0 = (const float*)d_in[4];
  const float* W1 = (const float*)d_in[5];  const float* b1 = (const float*)d_in[6];
  const float* W2 = (const float*)d_in[7];  const float* b2 = (const float*)d_in[8];
  const float* W3 = (const float*)d_in[9];  const float* b3 = (const float*)d_in[10];
  const float* eps = (const float*)d_in[11];

  char* w = (char*)d_ws;
  auto alloc = [&](size_t bytes)->char*{
    char* p = w; w += (bytes + 255) & ~(size_t)255; return p;
  };
  int*  gh    = (int*)alloc(sizeof(int)*NHIST);
  int*  gscan = (int*)alloc(sizeof(int)*NHIST);
  int*  bsum  = (int*)alloc(sizeof(int)*256);
  int*  boff  = (int*)alloc(sizeof(int)*256);
  int*  bstart= (int*)alloc(sizeof(int)*(NB+1));
  int*  offs  = (int*)alloc(sizeof(int)*NODES);
  int*  degs  = (int*)alloc(sizeof(int)*NODES);
  float* invd = (float*)alloc(sizeof(float)*NODES);
  u32*  elist = (u32*)alloc(sizeof(u32)*EDGES);
  u16*  hb    = (u16*)alloc(sizeof(u16)*(size_t)NODES*FEATS);
  u16*  yb    = (u16*)alloc(sizeof(u16)*(size_t)NODES*FEATS);
  u16*  Wt0   = (u16*)alloc(sizeof(u16)*128*128);
  u16*  Wt1   = (u16*)alloc(sizeof(u16)*128*128);
  u16*  Wt2   = (u16*)alloc(sizeof(u16)*128*128);
  u16*  Wt3   = (u16*)alloc(sizeof(u16)*16*128);

  // ---- deterministic 3-phase partition -> dense bucketed elist ----
  pA_k<<<NBLK, 256, 0, stream>>>(dst, gh, EDGES);
  int snb = (NHIST + 2047)/2048;                 // 150 <= 256
  scan1_k<<<snb, 256, 0, stream>>>(gh, gscan, bsum, NHIST);
  scan2_k<<<1, 256, 0, stream>>>(bsum, boff, snb);
  scan3_k<<<(NHIST+255)/256, 256, 0, stream>>>(gscan, boff, bstart, NHIST);
  pC_k<<<NBLK, 256, 0, stream>>>(src, dst, gscan, elist, EDGES);
  csr_k<<<NB, 256, 0, stream>>>(elist, bstart, offs, degs, invd, NODES);

  // ---- convert inputs to bf16 ----
  convf_k<<<((NODES*FEATS/4)+255)/256, 256, 0, stream>>>(feats, hb, NODES*FEATS/4);
  convw_k<<<(128*128+255)/256, 256, 0, stream>>>(W0, Wt0, 128, 128);
  convw_k<<<(128*128+255)/256, 256, 0, stream>>>(W1, Wt1, 128, 128);
  convw_k<<<(128*128+255)/256, 256, 0, stream>>>(W2, Wt2, 128, 128);
  convw_k<<<(128*16 +255)/256, 256, 0, stream>>>(W3, Wt3, 128, 16);

  int gblocks = (NODES + 63)/64;
  int ablocks = (NODES + 3)/4;

  // layers 0..2: y = h@W ; h = relu((1+eps)y + mean_agg(y) + b)
  gemm_k<8><<<gblocks, 256, 0, stream>>>(hb, Wt0, yb, NODES);
  aggL2_k<<<ablocks, 256, 0, stream>>>((const uint2*)yb, elist, offs, degs, invd, b0, eps, 0, (uint2*)hb, NODES);
  gemm_k<8><<<gblocks, 256, 0, stream>>>(hb, Wt1, yb, NODES);
  aggL2_k<<<ablocks, 256, 0, stream>>>((const uint2*)yb, elist, offs, degs, invd, b1, eps, 1, (uint2*)hb, NODES);
  gemm_k<8><<<gblocks, 256, 0, stream>>>(hb, Wt2, yb, NODES);
  aggL2_k<<<ablocks, 256, 0, stream>>>((const uint2*)yb, elist, offs, degs, invd, b2, eps, 2, (uint2*)hb, NODES);

  // layer 3: y = h@W3 (N=16); out = (1+eps)y + mean_agg(y) + b  (f32, no relu)
  gemm_k<1><<<gblocks, 256, 0, stream>>>(hb, Wt3, yb, NODES);
  aggF2_k<<<ablocks, 256, 0, stream>>>(yb, elist, offs, degs, invd, b3, eps, (float*)d_out, NODES);
}